// Round 16
// baseline (131.005 us; speedup 1.0000x reference)
//
#include <hip/hip_runtime.h>
#include <stdint.h>

#define BATCH 2
#define NPTS  4096
#define KNBR  32
#define TOKC  128

typedef _Float16 half8 __attribute__((ext_vector_type(8)));
typedef _Float16 half4 __attribute__((ext_vector_type(4)));
typedef float    f32x4 __attribute__((ext_vector_type(4)));

// ---------------- workspace layout (bytes) ----------------
// idx  : int      [2*4096*32] @ 0          (1 MB)
// Fh   : _Float16 [2*4096*128]@ 1 MB       (2 MB)
// Ah   : _Float16 [2*4096*128]@ 3 MB       (2 MB)
// W1F  : fp16 [ 8*512] @ 5MB+2048          (8 KB)   k_main W1rel frags
// W2F  : fp16 [32*512] @ 5MB+10240         (32 KB)  k_main W2 frags
// W1FA : fp16 [16*512] @ 5MB+43008         (16 KB)  prep feat-part frags
// W1FP : fp16 [24*512] @ 5MB+59392        (24 KB)  prep abs-pe frags
// SOA  : float xs/ys/zs [2*4096] each @ 5MB+83968 (96 KB)
// bmax : float [1024*128] @ 6 MB           (512 KB)
// bmax2: float [64*128]   @ 7 MB           (32 KB)
// cnt  : uint             @ 7 MB+32K
#define OFF_FH    (1u << 20)
#define OFF_AH    (3u << 20)
#define OFF_W1F   ((5u << 20) + 2048)
#define OFF_W2F   ((5u << 20) + 10240)
#define OFF_W1FA  ((5u << 20) + 43008)
#define OFF_W1FP  ((5u << 20) + 59392)
#define OFF_SOA   ((5u << 20) + 83968)
#define OFF_BMAX  (6u << 20)
#define OFF_BMAX2 (7u << 20)
#define OFF_CNT   ((7u << 20) + 32768)

#define NMAIN 1024

// ---------------- launch 0: SoA transpose + ALL weight repacks + counter init ----------------
__global__ __launch_bounds__(256) void k_soa(const float* __restrict__ xyz,
                                             const float* __restrict__ W1,
                                             const float* __restrict__ W2,
                                             float* __restrict__ soa,
                                             _Float16* __restrict__ W1F,
                                             _Float16* __restrict__ W2F,
                                             _Float16* __restrict__ W1FA,
                                             _Float16* __restrict__ W1FP,
                                             unsigned int* __restrict__ cntp) {
    const int t = threadIdx.x;
    if (blockIdx.x < 32) {
        // xyz AoS -> SoA (bit-exact copy): point p
        int p = blockIdx.x * 256 + t;                 // 0..8191 (b*4096+n)
        float x = xyz[p * 3 + 0], y = xyz[p * 3 + 1], z = xyz[p * 3 + 2];
        float* xs = soa;
        float* ys = soa + 8192;
        float* zs = soa + 16384;
        xs[p] = x; ys[p] = y; zs[p] = z;
        if (blockIdx.x == 0 && t == 0) *cntp = 0u;
        return;
    }
    // repack one 512-elem fragment: elem e -> lane=e>>3, j=e&7; lane: l15=lane&15, g=lane>>4
    int f = blockIdx.x - 32;                          // 0..79
    #pragma unroll
    for (int s = 0; s < 2; s++) {
        int e = t + s * 256;
        int ln = e >> 3, j = e & 7;
        int l15 = ln & 15, g = ln >> 4;
        if (f < 8) {                                  // k_main W1rel: tile f, K=32 (27..31 zero)
            int k = g * 8 + j;
            int c = f * 16 + l15;
            W1F[f * 512 + e] = (_Float16)((k < 27) ? W1[(64 + k) * TOKC + c] : 0.f);
        } else if (f < 40) {                          // k_main W2: frag (ct,kc)
            int f2 = f - 8;
            int ct = f2 >> 2, kc = f2 & 3;
            W2F[f2 * 512 + e] = (_Float16)W2[(kc * 32 + g * 8 + j) * TOKC + ct * 16 + l15];
        } else if (f < 56) {                          // prep feat part: rows 0..63
            int f3 = f - 40;
            int tile = f3 >> 1, kc = f3 & 1;
            W1FA[f3 * 512 + e] = (_Float16)W1[(kc * 32 + g * 8 + j) * TOKC + tile * 16 + l15];
        } else {                                      // prep abs-pe part: rows 91..186
            int f4 = f - 56;
            int tile = f4 / 3, kc = f4 % 3;
            W1FP[f4 * 512 + e] = (_Float16)W1[(91 + kc * 32 + g * 8 + j) * TOKC + tile * 16 + l15];
        }
    }
}

// ---------------- pass 1 (heterogeneous; prep FIRST so it hides under the search):
// 0..511     : F/A precompute via MFMA (16 points each, coalesced frag weights)
// 512..2559  : ball query (4 waves x 1 point each, SoA coords)
__global__ __launch_bounds__(256) void k_pre(const float* __restrict__ xyz,
                                             const float* __restrict__ feat,
                                             const float* __restrict__ b1,
                                             const float* __restrict__ soa,
                                             const _Float16* __restrict__ W1FA,
                                             const _Float16* __restrict__ W1FP,
                                             int* __restrict__ oidx,
                                             _Float16* __restrict__ Fh,
                                             _Float16* __restrict__ Ah) {
    __shared__ __align__(16) _Float16 inL[16][168];
    const int t = threadIdx.x;
    const int w = t >> 6, lane = t & 63;

    if (blockIdx.x >= 512) {
        // ---- ball query: SoA coords -> each wave-load covers 4 cachelines (was 12 with AoS).
        // 4-chunk unroll + register double-buffer; early exit every 256 candidates.
        int wave = (blockIdx.x - 512) * 4 + w;
        int b = wave >> 12;
        int n = wave & (NPTS - 1);
        const float* xs = soa + (size_t)b * NPTS;
        const float* ys = soa + 8192 + (size_t)b * NPTS;
        const float* zs = soa + 16384 + (size_t)b * NPTS;
        float cx = xs[n], cy = ys[n], cz = zs[n];
        const float R2 = 0.0256f;
        int cnt = 0;
        int first = 0;
        int* out = oidx + (size_t)wave * KNBR;
        float cur[12], nxt[12];
        #pragma unroll
        for (int u = 0; u < 4; u++) {
            int j = u * 64 + lane;
            cur[u * 3 + 0] = xs[j]; cur[u * 3 + 1] = ys[j]; cur[u * 3 + 2] = zs[j];
        }
        for (int base = 0; base < NPTS; base += 256) {
            #pragma clang fp contract(off)
            if (base + 256 < NPTS) {
                #pragma unroll
                for (int u = 0; u < 4; u++) {
                    int j = base + 256 + u * 64 + lane;
                    nxt[u * 3 + 0] = xs[j]; nxt[u * 3 + 1] = ys[j]; nxt[u * 3 + 2] = zs[j];
                }
            }
            #pragma unroll
            for (int u = 0; u < 4; u++) {
                float dx = cur[u * 3 + 0] - cx, dy = cur[u * 3 + 1] - cy, dz = cur[u * 3 + 2] - cz;
                float d2 = (dx * dx + dy * dy) + dz * dz;   // same op order as numpy, no fma
                bool hit = d2 <= R2;
                unsigned long long m = __ballot(hit);
                if (cnt == 0 && m) first = base + u * 64 + (int)__builtin_ctzll(m);
                if (hit) {
                    int pos = cnt + (int)__popcll(m & ((1ull << lane) - 1ull));
                    if (pos < KNBR) out[pos] = base + u * 64 + lane;
                }
                cnt += (int)__popcll(m);
            }
            if (cnt >= KNBR) break;
            #pragma unroll
            for (int i = 0; i < 12; i++) cur[i] = nxt[i];
        }
        if (lane >= cnt && lane < KNBR) out[lane] = first;
        return;
    }

    // ---- prep: F[j] = feat@W1[0:64], A[n] = abs_pe@W1[91:187]+b1, via MFMA ----
    // weight fragments now coalesced 16B/lane from repacked buffers (was 80 scalar loads)
    const int l15 = lane & 15, g = lane >> 4;
    const int g0 = blockIdx.x * 16;

    half8 af[2][2];
    half8 ap[2][3];
    float4 b1v[2];
    #pragma unroll
    for (int rt = 0; rt < 2; rt++) {
        #pragma unroll
        for (int kc = 0; kc < 2; kc++)
            af[rt][kc] = *(const half8*)&W1FA[(((2 * w + rt) * 2 + kc)) * 512 + lane * 8];
        #pragma unroll
        for (int kc = 0; kc < 3; kc++)
            ap[rt][kc] = *(const half8*)&W1FP[(((2 * w + rt) * 3 + kc)) * 512 + lane * 8];
        b1v[rt] = *(const float4*)&b1[32 * w + 16 * rt + g * 4];
    }

    {
        float4 v = ((const float4*)(feat + (size_t)g0 * 64))[t];
        half4 hv = {(_Float16)v.x, (_Float16)v.y, (_Float16)v.z, (_Float16)v.w};
        *(half4*)&inL[t >> 4][(t & 15) * 4] = hv;
    }
    {
        int p = t >> 4, v0 = (t & 15) * 6;
        const float* xp = xyz + (size_t)(g0 + p) * 3;
        #pragma unroll
        for (int u = 0; u < 6; u++) {
            int d = v0 + u;
            int a = d >> 5, i = d & 31, fi = i & 15;
            float fr = __expf(-0.6140226914650789f * (float)fi);  // ln(1e4)/15
            float ang = xp[a] * fr;
            inL[p][64 + d] = (_Float16)((i < 16) ? __sinf(ang) : __cosf(ang));
        }
    }
    __syncthreads();

    f32x4 cF[2], cA[2];
    #pragma unroll
    for (int rt = 0; rt < 2; rt++) { f32x4 z = {0.f, 0.f, 0.f, 0.f}; cF[rt] = z; cA[rt] = z; }
    #pragma unroll
    for (int kc = 0; kc < 2; kc++) {
        half8 bx = *(const half8*)&inL[l15][kc * 32 + g * 8];
        cF[0] = __builtin_amdgcn_mfma_f32_16x16x32_f16(af[0][kc], bx, cF[0], 0, 0, 0);
        cF[1] = __builtin_amdgcn_mfma_f32_16x16x32_f16(af[1][kc], bx, cF[1], 0, 0, 0);
    }
    #pragma unroll
    for (int kc = 0; kc < 3; kc++) {
        half8 bx = *(const half8*)&inL[l15][64 + kc * 32 + g * 8];
        cA[0] = __builtin_amdgcn_mfma_f32_16x16x32_f16(ap[0][kc], bx, cA[0], 0, 0, 0);
        cA[1] = __builtin_amdgcn_mfma_f32_16x16x32_f16(ap[1][kc], bx, cA[1], 0, 0, 0);
    }

    size_t pbase = ((size_t)g0 + l15) * TOKC;
    #pragma unroll
    for (int rt = 0; rt < 2; rt++) {
        int ch0 = 32 * w + 16 * rt + g * 4;
        half4 fv, av;
        #pragma unroll
        for (int r = 0; r < 4; r++) {
            fv[r] = (_Float16)cF[rt][r];
            av[r] = (_Float16)(cA[rt][r] + b1v[rt][r]);
        }
        *(half4*)&Fh[pbase + ch0] = fv;
        *(half4*)&Ah[pbase + ch0] = av;
    }
}

// ---------------- main: 1024 persistent blocks x 4 tiles (2 pts/64 pairs each) ----------------
// (256,3): proven VGPR~80, weights stay in registers. No global atomics (r5-r10 lesson).
__global__ __launch_bounds__(256, 3) void k_main(const float* __restrict__ xyz,
                                                 const int* __restrict__ idxw,
                                                 const _Float16* __restrict__ Fh,
                                                 const _Float16* __restrict__ Ah,
                                                 const _Float16* __restrict__ W1F,
                                                 const _Float16* __restrict__ W2F,
                                                 float* __restrict__ bmax) {
    __shared__ __align__(16) _Float16 xinL[64 * 40];
    __shared__ __align__(16) _Float16 hfa[64 * 136];
    __shared__ __align__(16) _Float16 arowL[256];
    __shared__ int jidxL[64];

    const int t = threadIdx.x;
    const int w = t >> 6, lane = t & 63;
    const int l15 = lane & 15, g = lane >> 4;
    const int b = blockIdx.x >> 9;
    const int pbase = (blockIdx.x & 511) * 8;
    const float* xb = xyz + (size_t)b * NPTS * 3;

    half8 a1[2];
    half8 a2[2][4];
    #pragma unroll
    for (int rt = 0; rt < 2; rt++) {
        a1[rt] = *(const half8*)&W1F[(2 * w + rt) * 512 + lane * 8];
        #pragma unroll
        for (int kc = 0; kc < 4; kc++)
            a2[rt][kc] = *(const half8*)&W2F[((2 * w + rt) * 4 + kc) * 512 + lane * 8];
    }

    float mxAll[2][4];
    #pragma unroll
    for (int rt = 0; rt < 2; rt++)
        #pragma unroll
        for (int r = 0; r < 4; r++) mxAll[rt][r] = -1e30f;

    const float FR[4] = {1.f, 0.0464158883f, 0.00215443469f, 1e-4f};

    int jreg = 0;
    ushort ar0;
    {
        const size_t gq = (size_t)b * NPTS + pbase;
        if (t < 64) jreg = idxw[gq * KNBR + t];
        ar0 = ((const ushort*)(Ah + gq * TOKC))[t];
    }

    for (int it = 0; it < 4; it++) {
        const int n0 = pbase + it * 2;
        const size_t gp0 = (size_t)b * NPTS + n0;

        if (t < 64) jidxL[t] = jreg;
        ((ushort*)arowL)[t] = ar0;
        __syncthreads();

        if (it < 3) {
            const size_t gq = gp0 + 2;
            if (t < 64) jreg = idxw[gq * KNBR + t];
            ar0 = ((const ushort*)(Ah + gq * TOKC))[t];
        }

        {
            int p = t >> 2, q = t & 3;
            int j = jidxL[p];
            const half8* frp = (const half8*)(Fh + ((size_t)b * NPTS + j) * TOKC + q * 32);
            half8 fb[4];
            #pragma unroll
            for (int i = 0; i < 4; i++) fb[i] = frp[i];
            const half8* arp = (const half8*)(arowL + (p >> 5) * TOKC + q * 32);
            half8* dst = (half8*)(hfa + p * 136 + q * 32);
            #pragma unroll
            for (int i = 0; i < 4; i++) dst[i] = fb[i] + arp[i];
        }
        if (t < 128) {
            int p = t >> 1, hh = t & 1;
            int n = n0 + (p >> 5), j = jidxL[p];
            float rx = xb[j * 3 + 0] - xb[n * 3 + 0];
            float ry = xb[j * 3 + 1] - xb[n * 3 + 1];
            float rz = xb[j * 3 + 2] - xb[n * 3 + 2];
            float v[16];
            if (hh == 0) {
                v[0] = rx; v[1] = ry; v[2] = rz;
                #pragma unroll
                for (int fi = 0; fi < 4; fi++) {
                    float ang = rx * FR[fi];
                    v[3 + fi] = __sinf(ang);
                    v[7 + fi] = __cosf(ang);
                }
                #pragma unroll
                for (int fi = 0; fi < 4; fi++) v[11 + fi] = __sinf(ry * FR[fi]);
                v[15] = __cosf(ry * FR[0]);
            } else {
                #pragma unroll
                for (int fi = 1; fi < 4; fi++) v[fi - 1] = __cosf(ry * FR[fi]);
                #pragma unroll
                for (int fi = 0; fi < 4; fi++) {
                    float ang = rz * FR[fi];
                    v[3 + fi] = __sinf(ang);
                    v[7 + fi] = __cosf(ang);
                }
                #pragma unroll
                for (int i = 11; i < 16; i++) v[i] = 0.f;
            }
            half8 h0, h1;
            #pragma unroll
            for (int i = 0; i < 8; i++) { h0[i] = (_Float16)v[i]; h1[i] = (_Float16)v[8 + i]; }
            *(half8*)&xinL[p * 40 + hh * 16]     = h0;
            *(half8*)&xinL[p * 40 + hh * 16 + 8] = h1;
        }
        __syncthreads();

        #pragma unroll
        for (int ct = 0; ct < 4; ct++) {
            int p = ct * 16 + l15;
            half8 bx = *(const half8*)&xinL[p * 40 + g * 8];
            f32x4 z = {0.f, 0.f, 0.f, 0.f};
            f32x4 c1a = __builtin_amdgcn_mfma_f32_16x16x32_f16(a1[0], bx, z, 0, 0, 0);
            f32x4 c1b = __builtin_amdgcn_mfma_f32_16x16x32_f16(a1[1], bx, z, 0, 0, 0);
            #pragma unroll
            for (int rt = 0; rt < 2; rt++) {
                int ch0 = 32 * w + 16 * rt + g * 4;
                half4* hp = (half4*)&hfa[p * 136 + ch0];
                half4 bias = *hp;
                f32x4 cc = rt ? c1b : c1a;
                half4 hv;
                #pragma unroll
                for (int r = 0; r < 4; r++) {
                    float s = cc[r] + (float)bias[r];
                    hv[r] = (_Float16)fmaxf(s, 0.f);
                }
                *hp = hv;
            }
        }
        __syncthreads();

        f32x4 c2[4][2];
        #pragma unroll
        for (int ct = 0; ct < 4; ct++)
            #pragma unroll
            for (int rt = 0; rt < 2; rt++) {
                f32x4 z = {0.f, 0.f, 0.f, 0.f};
                c2[ct][rt] = z;
            }
        #pragma unroll
        for (int kc = 0; kc < 4; kc++) {
            #pragma unroll
            for (int ct = 0; ct < 4; ct++) {
                half8 bx = *(const half8*)&hfa[(ct * 16 + l15) * 136 + kc * 32 + g * 8];
                c2[ct][0] = __builtin_amdgcn_mfma_f32_16x16x32_f16(a2[0][kc], bx, c2[ct][0], 0, 0, 0);
                c2[ct][1] = __builtin_amdgcn_mfma_f32_16x16x32_f16(a2[1][kc], bx, c2[ct][1], 0, 0, 0);
            }
        }
        #pragma unroll
        for (int rt = 0; rt < 2; rt++)
            #pragma unroll
            for (int r = 0; r < 4; r++) {
                float m0 = fmaxf(fmaxf(c2[0][rt][r], c2[1][rt][r]), fmaxf(c2[2][rt][r], c2[3][rt][r]));
                mxAll[rt][r] = fmaxf(mxAll[rt][r], m0);
            }
        __syncthreads();
    }

    #pragma unroll
    for (int rt = 0; rt < 2; rt++)
        #pragma unroll
        for (int r = 0; r < 4; r++)
            #pragma unroll
            for (int off = 1; off < 16; off <<= 1)
                mxAll[rt][r] = fmaxf(mxAll[rt][r], __shfl_xor(mxAll[rt][r], off));

    if (l15 == 0) {
        float* brow = bmax + (size_t)blockIdx.x * TOKC;
        float4 v0 = make_float4(mxAll[0][0], mxAll[0][1], mxAll[0][2], mxAll[0][3]);
        float4 v1 = make_float4(mxAll[1][0], mxAll[1][1], mxAll[1][2], mxAll[1][3]);
        *(float4*)&brow[32 * w + g * 4]      = v0;
        *(float4*)&brow[32 * w + 16 + g * 4] = v1;
    }
}

// ---------------- fused reduce + tail (last-done pattern; distinct-line atomic reads) ----------
__global__ __launch_bounds__(256) void k_redtail(const float* __restrict__ bmax,
                                                 float* __restrict__ bmax2,
                                                 unsigned int* __restrict__ cntp,
                                                 const float* __restrict__ b2,
                                                 const float* __restrict__ W3,
                                                 const float* __restrict__ b3,
                                                 const float* __restrict__ W4,
                                                 const float* __restrict__ b4,
                                                 float* __restrict__ out) {
    __shared__ float red[256];
    __shared__ float gl[256], sl[256];
    __shared__ unsigned int lastFlag;
    const int i = blockIdx.x, t = threadIdx.x;
    const int c = t & 127, h = t >> 7;
    {
        const float* base = bmax + ((size_t)i * 16 + (size_t)h * 8) * TOKC + c;
        float m = -1e30f;
        #pragma unroll
        for (int k = 0; k < 8; k++) m = fmaxf(m, base[(size_t)k * TOKC]);
        red[t] = m;
    }
    __syncthreads();
    if (t < 128) bmax2[(size_t)i * TOKC + t] = fmaxf(red[t], red[t + 128]);
    __threadfence();
    __syncthreads();
    if (t == 0) lastFlag = (atomicAdd(cntp, 1u) == 63u) ? 1u : 0u;
    __syncthreads();
    if (!lastFlag) return;

    const int bb = h;
    {
        unsigned int* bp = (unsigned int*)bmax2 + (size_t)bb * 32 * TOKC + c;
        float m = -1e30f;
        #pragma unroll
        for (int k = 0; k < 32; k++) {
            unsigned int u = atomicOr(&bp[(size_t)k * TOKC], 0u);
            m = fmaxf(m, __uint_as_float(u));
        }
        gl[t] = m + b2[c];
    }
    __syncthreads();
    {
        float s = b3[c];
        for (int k = 0; k < 128; k++) s += gl[bb * 128 + k] * W3[k * TOKC + c];
        sl[t] = fmaxf(s, 0.f);
    }
    __syncthreads();
    {
        float o = b4[c];
        for (int k = 0; k < 128; k++) o += sl[bb * 128 + k] * W4[k * TOKC + c];
        out[t] = o;
    }
}

extern "C" void kernel_launch(void* const* d_in, const int* in_sizes, int n_in,
                              void* d_out, int out_size, void* d_ws, size_t ws_size,
                              hipStream_t stream) {
    const float* xyz  = (const float*)d_in[0];
    const float* feat = (const float*)d_in[1];
    const float* W1   = (const float*)d_in[2];
    const float* b1   = (const float*)d_in[3];
    const float* W2   = (const float*)d_in[4];
    const float* b2   = (const float*)d_in[5];
    const float* W3   = (const float*)d_in[6];
    const float* b3   = (const float*)d_in[7];
    const float* W4   = (const float*)d_in[8];
    const float* b4   = (const float*)d_in[9];

    char* ws = (char*)d_ws;
    int*          idxw  = (int*)ws;
    _Float16*     Fh    = (_Float16*)(ws + OFF_FH);
    _Float16*     Ah    = (_Float16*)(ws + OFF_AH);
    _Float16*     W1F   = (_Float16*)(ws + OFF_W1F);
    _Float16*     W2F   = (_Float16*)(ws + OFF_W2F);
    _Float16*     W1FA  = (_Float16*)(ws + OFF_W1FA);
    _Float16*     W1FP  = (_Float16*)(ws + OFF_W1FP);
    float*        soa   = (float*)(ws + OFF_SOA);
    float*        bmax  = (float*)(ws + OFF_BMAX);
    float*        bmax2 = (float*)(ws + OFF_BMAX2);
    unsigned int* cntp  = (unsigned int*)(ws + OFF_CNT);

    // L0: SoA transpose (32) + all weight repacks (80) + counter init
    k_soa<<<dim3(112), dim3(256), 0, stream>>>(xyz, W1, W2, soa, W1F, W2F, W1FA, W1FP, cntp);
    // L1: prep (512, first) + search (2048), heterogeneous
    k_pre<<<dim3(2560), dim3(256), 0, stream>>>(xyz, feat, b1, soa, W1FA, W1FP, idxw, Fh, Ah);
    // L2: main MLP + per-block max (persistent, plain stores)
    k_main<<<dim3(NMAIN), dim3(256), 0, stream>>>(xyz, idxw, Fh, Ah, W1F, W2F, bmax);
    // L3: cross-block max reduce + fused final MLP (last-done)
    k_redtail<<<dim3(64), dim3(256), 0, stream>>>(bmax, bmax2, cntp,
                                                  b2, W3, b3, W4, b4, (float*)d_out);
}

// Round 17
// 123.833 us; speedup vs baseline: 1.0579x; 1.0579x over previous
//
#include <hip/hip_runtime.h>
#include <stdint.h>

#define BATCH 2
#define NPTS  4096
#define KNBR  32
#define TOKC  128

typedef _Float16 half8 __attribute__((ext_vector_type(8)));
typedef _Float16 half4 __attribute__((ext_vector_type(4)));
typedef float    f32x4 __attribute__((ext_vector_type(4)));

// ---------------- workspace layout (bytes) ----------------
// idx  : int      [2*4096*32] @ 0       (1 MB)
// Fh   : _Float16 [2*4096*128]@ 1 MB    (2 MB)
// Ah   : _Float16 [2*4096*128]@ 3 MB    (2 MB)
// W1F  : _Float16 [8*512]  @ 5MB+2048   (8 KB)
// W2F  : _Float16 [32*512] @ 5MB+10240  (32 KB)
// bmax : float    [1024*128] @ 6 MB     (512 KB) per-block maxima (plain stores)
// bmax2: float    [64*128]   @ 7 MB     (32 KB)  stage-1 reduced maxima
#define OFF_FH    (1u << 20)
#define OFF_AH    (3u << 20)
#define OFF_W1F   ((5u << 20) + 2048)
#define OFF_W2F   ((5u << 20) + 10240)
#define OFF_BMAX  (6u << 20)
#define OFF_BMAX2 (7u << 20)

#define NMAIN 1024   // k_main grid (each block: 8 points = 4 tiles x 2 points)

// ---------------- pass 1 (heterogeneous blocks):
// 0..2047    : ball query (4 waves x 1 point each)
// 2048..2559 : F/A precompute via MFMA (16 points each)
// 2560..2599 : weight repack to frag order
__global__ __launch_bounds__(256) void k_pre(const float* __restrict__ xyz,
                                             const float* __restrict__ feat,
                                             const float* __restrict__ W1,
                                             const float* __restrict__ W2,
                                             const float* __restrict__ b1,
                                             int* __restrict__ oidx,
                                             _Float16* __restrict__ Fh,
                                             _Float16* __restrict__ Ah,
                                             _Float16* __restrict__ W1F,
                                             _Float16* __restrict__ W2F) {
    __shared__ __align__(16) _Float16 inL[16][168];
    const int t = threadIdx.x;
    const int w = t >> 6, lane = t & 63;

    if (blockIdx.x < 2048) {
        // ---- ball query: one wave per point, 4-chunk unrolled scan + early exit.
        // r13 evidence: per-chunk s_waitcnt vmcnt(0) -> ~200cyc stall each 64 candidates
        // (VALUBusy 24%). 12 loads issued together = one stall per 256 candidates; exit
        // check every 4 chunks (avg needed ~30 chunks). Per-chunk logic order-identical.
        int wave = blockIdx.x * 4 + w;
        int b = wave >> 12;
        int n = wave & (NPTS - 1);
        const float* xb = xyz + (size_t)b * NPTS * 3;
        float cx = xb[n * 3 + 0], cy = xb[n * 3 + 1], cz = xb[n * 3 + 2];
        const float R2 = 0.0256f;
        int cnt = 0;
        int first = 0;
        int* out = oidx + (size_t)wave * KNBR;
        for (int base = 0; base < NPTS; base += 256) {
            #pragma clang fp contract(off)
            float pxv[4], pyv[4], pzv[4];
            #pragma unroll
            for (int u = 0; u < 4; u++) {
                int j = base + u * 64 + lane;
                pxv[u] = xb[j * 3 + 0];
                pyv[u] = xb[j * 3 + 1];
                pzv[u] = xb[j * 3 + 2];
            }
            #pragma unroll
            for (int u = 0; u < 4; u++) {
                float dx = pxv[u] - cx, dy = pyv[u] - cy, dz = pzv[u] - cz;
                float d2 = (dx * dx + dy * dy) + dz * dz;   // same op order as numpy, no fma
                bool hit = d2 <= R2;
                unsigned long long m = __ballot(hit);
                if (cnt == 0 && m) first = base + u * 64 + (int)__builtin_ctzll(m);
                if (hit) {
                    int pos = cnt + (int)__popcll(m & ((1ull << lane) - 1ull));
                    if (pos < KNBR) out[pos] = base + u * 64 + lane;
                }
                cnt += (int)__popcll(m);
            }
            if (cnt >= KNBR) break;
        }
        if (lane >= cnt && lane < KNBR) out[lane] = first;
        return;
    }

    if (blockIdx.x >= 2560) {
        // ---- weight repack to A-fragment order ----
        int f = blockIdx.x - 2560;           // 0..39
        #pragma unroll
        for (int s = 0; s < 2; s++) {
            int e = t + s * 256;
            int ln = e >> 3, j = e & 7;
            int l15 = ln & 15, g = ln >> 4;
            if (f < 8) {                     // W1rel: ch tile f, K=32 (rows 27..31 zero)
                int k = g * 8 + j;
                int c = f * 16 + l15;
                float val = (k < 27) ? W1[(64 + k) * TOKC + c] : 0.f;
                W1F[f * 512 + e] = (_Float16)val;
            } else {                         // W2: frag (ct,kc)
                int f2 = f - 8;
                int ct = f2 >> 2, kc = f2 & 3;
                int k = kc * 32 + g * 8 + j;
                int c = ct * 16 + l15;
                W2F[f2 * 512 + e] = (_Float16)W2[k * TOKC + c];
            }
        }
        return;
    }

    // ---- prep: F[j] = feat@W1[0:64], A[n] = abs_pe@W1[91:187]+b1, via MFMA ----
    const int l15 = lane & 15, g = lane >> 4;
    const int g0 = (blockIdx.x - 2048) * 16;

    half8 af[2][2];
    half8 ap[2][3];
    float4 b1v[2];
    #pragma unroll
    for (int rt = 0; rt < 2; rt++) {
        int c = 32 * w + 16 * rt + l15;
        #pragma unroll
        for (int kc = 0; kc < 2; kc++)
            #pragma unroll
            for (int j = 0; j < 8; j++)
                af[rt][kc][j] = (_Float16)W1[(kc * 32 + g * 8 + j) * TOKC + c];
        #pragma unroll
        for (int kc = 0; kc < 3; kc++)
            #pragma unroll
            for (int j = 0; j < 8; j++)
                ap[rt][kc][j] = (_Float16)W1[(91 + kc * 32 + g * 8 + j) * TOKC + c];
        b1v[rt] = *(const float4*)&b1[32 * w + 16 * rt + g * 4];
    }

    {
        float4 v = ((const float4*)(feat + (size_t)g0 * 64))[t];
        half4 hv = {(_Float16)v.x, (_Float16)v.y, (_Float16)v.z, (_Float16)v.w};
        *(half4*)&inL[t >> 4][(t & 15) * 4] = hv;
    }
    {
        int p = t >> 4, v0 = (t & 15) * 6;
        const float* xp = xyz + (size_t)(g0 + p) * 3;
        #pragma unroll
        for (int u = 0; u < 6; u++) {
            int d = v0 + u;
            int a = d >> 5, i = d & 31, fi = i & 15;
            float fr = __expf(-0.6140226914650789f * (float)fi);  // ln(1e4)/15
            float ang = xp[a] * fr;
            inL[p][64 + d] = (_Float16)((i < 16) ? __sinf(ang) : __cosf(ang));
        }
    }
    __syncthreads();

    f32x4 cF[2], cA[2];
    #pragma unroll
    for (int rt = 0; rt < 2; rt++) { f32x4 z = {0.f, 0.f, 0.f, 0.f}; cF[rt] = z; cA[rt] = z; }
    #pragma unroll
    for (int kc = 0; kc < 2; kc++) {
        half8 bx = *(const half8*)&inL[l15][kc * 32 + g * 8];
        cF[0] = __builtin_amdgcn_mfma_f32_16x16x32_f16(af[0][kc], bx, cF[0], 0, 0, 0);
        cF[1] = __builtin_amdgcn_mfma_f32_16x16x32_f16(af[1][kc], bx, cF[1], 0, 0, 0);
    }
    #pragma unroll
    for (int kc = 0; kc < 3; kc++) {
        half8 bx = *(const half8*)&inL[l15][64 + kc * 32 + g * 8];
        cA[0] = __builtin_amdgcn_mfma_f32_16x16x32_f16(ap[0][kc], bx, cA[0], 0, 0, 0);
        cA[1] = __builtin_amdgcn_mfma_f32_16x16x32_f16(ap[1][kc], bx, cA[1], 0, 0, 0);
    }

    size_t pbase = ((size_t)g0 + l15) * TOKC;
    #pragma unroll
    for (int rt = 0; rt < 2; rt++) {
        int ch0 = 32 * w + 16 * rt + g * 4;
        half4 fv, av;
        #pragma unroll
        for (int r = 0; r < 4; r++) {
            fv[r] = (_Float16)cF[rt][r];
            av[r] = (_Float16)(cA[rt][r] + b1v[rt][r]);
        }
        *(half4*)&Fh[pbase + ch0] = fv;
        *(half4*)&Ah[pbase + ch0] = av;
    }
}

// ---------------- main: 1024 persistent blocks x 4 tiles (2 pts/64 pairs each) ----------------
// (256,3): proven (r7) VGPR~80, weights stay in registers. No global atomics (r5-r10 lesson).
__global__ __launch_bounds__(256, 3) void k_main(const float* __restrict__ xyz,
                                                 const int* __restrict__ idxw,
                                                 const _Float16* __restrict__ Fh,
                                                 const _Float16* __restrict__ Ah,
                                                 const _Float16* __restrict__ W1F,
                                                 const _Float16* __restrict__ W2F,
                                                 float* __restrict__ bmax) {
    __shared__ __align__(16) _Float16 xinL[64 * 40];    // [pair][k32+pad8]   5 KB
    __shared__ __align__(16) _Float16 hfa[64 * 136];    // [pair][ch128+pad8] 17 KB
    __shared__ __align__(16) _Float16 arowL[256];       // 2 rows x 128 ch
    __shared__ int jidxL[64];

    const int t = threadIdx.x;
    const int w = t >> 6, lane = t & 63;
    const int l15 = lane & 15, g = lane >> 4;
    const int b = blockIdx.x >> 9;             // 512 blocks per batch
    const int pbase = (blockIdx.x & 511) * 8;  // 8 points per block
    const float* xb = xyz + (size_t)b * NPTS * 3;

    // coalesced persistent A-fragments (16B/lane, frag-ordered buffers), loaded once per block
    half8 a1[2];
    half8 a2[2][4];
    #pragma unroll
    for (int rt = 0; rt < 2; rt++) {
        a1[rt] = *(const half8*)&W1F[(2 * w + rt) * 512 + lane * 8];
        #pragma unroll
        for (int kc = 0; kc < 4; kc++)
            a2[rt][kc] = *(const half8*)&W2F[((2 * w + rt) * 4 + kc) * 512 + lane * 8];
    }

    float mxAll[2][4];
    #pragma unroll
    for (int rt = 0; rt < 2; rt++)
        #pragma unroll
        for (int r = 0; r < 4; r++) mxAll[rt][r] = -1e30f;

    const float FR[4] = {1.f, 0.0464158883f, 0.00215443469f, 1e-4f};

    // prefetch tile 0's idx + A rows into registers
    int jreg = 0;
    ushort ar0;
    {
        const size_t gq = (size_t)b * NPTS + pbase;
        if (t < 64) jreg = idxw[gq * KNBR + t];
        ar0 = ((const ushort*)(Ah + gq * TOKC))[t];
    }

    for (int it = 0; it < 4; it++) {
        const int n0 = pbase + it * 2;
        const size_t gp0 = (size_t)b * NPTS + n0;

        if (t < 64) jidxL[t] = jreg;
        ((ushort*)arowL)[t] = ar0;
        __syncthreads();

        // issue next tile's prefetch (completes during this tile's compute)
        if (it < 3) {
            const size_t gq = gp0 + 2;
            if (t < 64) jreg = idxw[gq * KNBR + t];
            ar0 = ((const ushort*)(Ah + gq * TOKC))[t];
        }

        // --- staging: hfa by all 256 (p=t>>2, 32 ch each); xin by t<128 (p=t>>1, 16 dims) ---
        {
            int p = t >> 2, q = t & 3;
            int j = jidxL[p];
            const half8* frp = (const half8*)(Fh + ((size_t)b * NPTS + j) * TOKC + q * 32);
            half8 fb[4];
            #pragma unroll
            for (int i = 0; i < 4; i++) fb[i] = frp[i];
            const half8* arp = (const half8*)(arowL + (p >> 5) * TOKC + q * 32);
            half8* dst = (half8*)(hfa + p * 136 + q * 32);
            #pragma unroll
            for (int i = 0; i < 4; i++) dst[i] = fb[i] + arp[i];
        }
        if (t < 128) {
            int p = t >> 1, hh = t & 1;
            int n = n0 + (p >> 5), j = jidxL[p];
            float rx = xb[j * 3 + 0] - xb[n * 3 + 0];
            float ry = xb[j * 3 + 1] - xb[n * 3 + 1];
            float rz = xb[j * 3 + 2] - xb[n * 3 + 2];
            float v[16];
            if (hh == 0) {
                v[0] = rx; v[1] = ry; v[2] = rz;
                #pragma unroll
                for (int fi = 0; fi < 4; fi++) {
                    float ang = rx * FR[fi];
                    v[3 + fi] = __sinf(ang);
                    v[7 + fi] = __cosf(ang);
                }
                #pragma unroll
                for (int fi = 0; fi < 4; fi++) v[11 + fi] = __sinf(ry * FR[fi]);
                v[15] = __cosf(ry * FR[0]);
            } else {
                #pragma unroll
                for (int fi = 1; fi < 4; fi++) v[fi - 1] = __cosf(ry * FR[fi]);
                #pragma unroll
                for (int fi = 0; fi < 4; fi++) {
                    float ang = rz * FR[fi];
                    v[3 + fi] = __sinf(ang);
                    v[7 + fi] = __cosf(ang);
                }
                #pragma unroll
                for (int i = 11; i < 16; i++) v[i] = 0.f;
            }
            half8 h0, h1;
            #pragma unroll
            for (int i = 0; i < 8; i++) { h0[i] = (_Float16)v[i]; h1[i] = (_Float16)v[8 + i]; }
            *(half8*)&xinL[p * 40 + hh * 16]     = h0;
            *(half8*)&xinL[p * 40 + hh * 16 + 8] = h1;
        }
        __syncthreads();

        // --- phase 1: h1^T = W1rel^T * xin^T, in-place relu(c1 + F + A) into hfa ---
        #pragma unroll
        for (int ct = 0; ct < 4; ct++) {
            int p = ct * 16 + l15;
            half8 bx = *(const half8*)&xinL[p * 40 + g * 8];
            f32x4 z = {0.f, 0.f, 0.f, 0.f};
            f32x4 c1a = __builtin_amdgcn_mfma_f32_16x16x32_f16(a1[0], bx, z, 0, 0, 0);
            f32x4 c1b = __builtin_amdgcn_mfma_f32_16x16x32_f16(a1[1], bx, z, 0, 0, 0);
            #pragma unroll
            for (int rt = 0; rt < 2; rt++) {
                int ch0 = 32 * w + 16 * rt + g * 4;
                half4* hp = (half4*)&hfa[p * 136 + ch0];
                half4 bias = *hp;
                f32x4 cc = rt ? c1b : c1a;
                half4 hv;
                #pragma unroll
                for (int r = 0; r < 4; r++) {
                    float s = cc[r] + (float)bias[r];
                    hv[r] = (_Float16)fmaxf(s, 0.f);
                }
                *hp = hv;
            }
        }
        __syncthreads();

        // --- phase 2: h2^T = W2^T * h1^T, fold max over pairs ---
        f32x4 c2[4][2];
        #pragma unroll
        for (int ct = 0; ct < 4; ct++)
            #pragma unroll
            for (int rt = 0; rt < 2; rt++) {
                f32x4 z = {0.f, 0.f, 0.f, 0.f};
                c2[ct][rt] = z;
            }
        #pragma unroll
        for (int kc = 0; kc < 4; kc++) {
            #pragma unroll
            for (int ct = 0; ct < 4; ct++) {
                half8 bx = *(const half8*)&hfa[(ct * 16 + l15) * 136 + kc * 32 + g * 8];
                c2[ct][0] = __builtin_amdgcn_mfma_f32_16x16x32_f16(a2[0][kc], bx, c2[ct][0], 0, 0, 0);
                c2[ct][1] = __builtin_amdgcn_mfma_f32_16x16x32_f16(a2[1][kc], bx, c2[ct][1], 0, 0, 0);
            }
        }
        #pragma unroll
        for (int rt = 0; rt < 2; rt++)
            #pragma unroll
            for (int r = 0; r < 4; r++) {
                float m0 = fmaxf(fmaxf(c2[0][rt][r], c2[1][rt][r]), fmaxf(c2[2][rt][r], c2[3][rt][r]));
                mxAll[rt][r] = fmaxf(mxAll[rt][r], m0);
            }
        __syncthreads();   // protect LDS before next iteration's staging
    }

    // reduce over the 16 pair-columns in-register, then ONE plain store row per block
    #pragma unroll
    for (int rt = 0; rt < 2; rt++)
        #pragma unroll
        for (int r = 0; r < 4; r++)
            #pragma unroll
            for (int off = 1; off < 16; off <<= 1)
                mxAll[rt][r] = fmaxf(mxAll[rt][r], __shfl_xor(mxAll[rt][r], off));

    if (l15 == 0) {
        float* brow = bmax + (size_t)blockIdx.x * TOKC;
        float4 v0 = make_float4(mxAll[0][0], mxAll[0][1], mxAll[0][2], mxAll[0][3]);
        float4 v1 = make_float4(mxAll[1][0], mxAll[1][1], mxAll[1][2], mxAll[1][3]);
        *(float4*)&brow[32 * w + g * 4]      = v0;   // rt=0: ch = 32w+4g+r
        *(float4*)&brow[32 * w + 16 + g * 4] = v1;   // rt=1: ch = 32w+16+4g+r
    }
}

// ---------------- stage-1 reduce: 64 blocks, each max-reduces 16 rows of bmax ----------------
__global__ __launch_bounds__(256) void k_red(const float* __restrict__ bmax,
                                             float* __restrict__ bmax2) {
    __shared__ float red[256];
    const int i = blockIdx.x, t = threadIdx.x;
    const int c = t & 127, h = t >> 7;
    const float* base = bmax + ((size_t)i * 16 + (size_t)h * 8) * TOKC + c;
    float m = -1e30f;
    #pragma unroll
    for (int k = 0; k < 8; k++) m = fmaxf(m, base[(size_t)k * TOKC]);
    red[t] = m;
    __syncthreads();
    if (t < 128) bmax2[(size_t)i * TOKC + t] = fmaxf(red[t], red[t + 128]);
}

// ---------------- stage-2: reduce 32 rows of bmax2 per batch + final tiny MLP ----------------
__global__ __launch_bounds__(256) void k_tail(const float* __restrict__ bmax2,
                                              const float* __restrict__ b2,
                                              const float* __restrict__ W3,
                                              const float* __restrict__ b3,
                                              const float* __restrict__ W4,
                                              const float* __restrict__ b4,
                                              float* __restrict__ out) {
    __shared__ float red[256];
    __shared__ float gl[128], sl[128];
    const int b = blockIdx.x, t = threadIdx.x;
    const int c = t & 127, h = t >> 7;
    const float* base = bmax2 + ((size_t)b * 32 + (size_t)h * 16) * TOKC + c;
    float m = -1e30f;
    #pragma unroll
    for (int k = 0; k < 16; k++) m = fmaxf(m, base[(size_t)k * TOKC]);
    red[t] = m;
    __syncthreads();
    if (t < 128) gl[t] = fmaxf(red[t], red[t + 128]) + b2[t];   // b2 folded post-max
    __syncthreads();
    if (t < 128) {
        float s = b3[t];
        for (int k = 0; k < 128; k++) s += gl[k] * W3[k * TOKC + t];
        sl[t] = fmaxf(s, 0.f);
    }
    __syncthreads();
    if (t < 128) {
        float o = b4[t];
        for (int k = 0; k < 128; k++) o += sl[k] * W4[k * TOKC + t];
        out[b * TOKC + t] = o;
    }
}

extern "C" void kernel_launch(void* const* d_in, const int* in_sizes, int n_in,
                              void* d_out, int out_size, void* d_ws, size_t ws_size,
                              hipStream_t stream) {
    const float* xyz  = (const float*)d_in[0];
    const float* feat = (const float*)d_in[1];
    const float* W1   = (const float*)d_in[2];
    const float* b1   = (const float*)d_in[3];
    const float* W2   = (const float*)d_in[4];
    const float* b2   = (const float*)d_in[5];
    const float* W3   = (const float*)d_in[6];
    const float* b3   = (const float*)d_in[7];
    const float* W4   = (const float*)d_in[8];
    const float* b4   = (const float*)d_in[9];

    char* ws = (char*)d_ws;
    int*          idxw  = (int*)ws;
    _Float16*     Fh    = (_Float16*)(ws + OFF_FH);
    _Float16*     Ah    = (_Float16*)(ws + OFF_AH);
    _Float16*     W1F   = (_Float16*)(ws + OFF_W1F);
    _Float16*     W2F   = (_Float16*)(ws + OFF_W2F);
    float*        bmax  = (float*)(ws + OFF_BMAX);
    float*        bmax2 = (float*)(ws + OFF_BMAX2);

    // L1: search (2048) + prep (512) + repack (40), heterogeneous
    k_pre<<<dim3(2600), dim3(256), 0, stream>>>(xyz, feat, W1, W2, b1,
                                                idxw, Fh, Ah, W1F, W2F);
    // L2: main MLP + per-block max (persistent, plain stores)
    k_main<<<dim3(NMAIN), dim3(256), 0, stream>>>(xyz, idxw, Fh, Ah, W1F, W2F, bmax);
    // L3: stage-1 cross-block max (64 blocks)
    k_red<<<dim3(64), dim3(256), 0, stream>>>(bmax, bmax2);
    // L4: stage-2 max + final tiny MLP (2 blocks)
    k_tail<<<dim3(BATCH), dim3(256), 0, stream>>>(bmax2, b2, W3, b3, W4, b4, (float*)d_out);
}